// Round 2
// baseline (251.490 us; speedup 1.0000x reference)
//
#include <hip/hip_runtime.h>

typedef __bf16 bf16x8 __attribute__((ext_vector_type(8)));
typedef __bf16 bf16x4 __attribute__((ext_vector_type(4)));
typedef float f32x4 __attribute__((ext_vector_type(4)));

typedef const __attribute__((address_space(1))) void* gptr_t;
typedef __attribute__((address_space(3))) void* lptr_t;

__device__ __forceinline__ f32x4 mfma16(bf16x8 a, bf16x8 b, f32x4 c) {
  return __builtin_amdgcn_mfma_f32_16x16x32_bf16(a, b, c, 0, 0, 0);
}

__device__ __forceinline__ void load_lds16(const __bf16* g, __bf16* l) {
  __builtin_amdgcn_global_load_lds((gptr_t)g, (lptr_t)l, 16, 0, 0);
}

__device__ __forceinline__ float fast_exp2(float x) {
#if __has_builtin(__builtin_amdgcn_exp2f)
  return __builtin_amdgcn_exp2f(x);  // raw v_exp_f32
#else
  return exp2f(x);
#endif
}

// round-to-nearest(+away) f32->bf16 for two values, packed into one dword
__device__ __forceinline__ unsigned pack_bf16(float f0, float f1) {
  unsigned u0 = __builtin_bit_cast(unsigned, f0) + 0x8000u;
  unsigned u1 = __builtin_bit_cast(unsigned, f1) + 0x8000u;
  return __builtin_amdgcn_perm(u1, u0, 0x07060302);
}

// ---- fp32 -> bf16 pre-convert: x (4096 blks), qkv_w (1536), out_w (512) ----
__global__ __launch_bounds__(256) void convert3(
    const float* __restrict__ x, const float* __restrict__ w1,
    const float* __restrict__ w2, __bf16* __restrict__ xb,
    __bf16* __restrict__ w1b, __bf16* __restrict__ w2b) {
  int bid = blockIdx.x;
  const float* src;
  __bf16* dst;
  int base;
  if (bid < 4096) {
    src = x; dst = xb; base = bid;
  } else if (bid < 5632) {
    src = w1; dst = w1b; base = bid - 4096;
  } else {
    src = w2; dst = w2b; base = bid - 5632;
  }
  size_t off = (size_t)base * 2048 + threadIdx.x * 8;
  float4 v0 = *(const float4*)(src + off);
  float4 v1 = *(const float4*)(src + off + 4);
  bf16x8 o = {(__bf16)v0.x, (__bf16)v0.y, (__bf16)v0.z, (__bf16)v0.w,
              (__bf16)v1.x, (__bf16)v1.y, (__bf16)v1.z, (__bf16)v1.w};
  *(bf16x8*)(dst + off) = o;
}

// ---------------------------------------------------------------------------
// 256x256 8-phase pipelined GEMM (m201 template port, plain HIP).
// C[M][N] = A[M][K] @ B[N][K]^T + bias[N].
// 8 waves (2M x 4N), per-wave 128x64 output, BK=64, LDS 128 KiB:
//   per matrix [2 slots][2 halves][128 rows][64 k] bf16.
// Octet-XOR swizzle (proven): LDS position p of row r holds global octet
// p ^ (r&7); fragment read at octet (4*ksi+quad) ^ (l15&7). Balanced:
// 8 lanes per 4-bank group = LDS natural throughput, zero excess cycles.
// Staging via global_load_lds(16B): linear LDS dest, pre-swizzled global src.
//
// Schedule per iteration i (2 K-tiles: t=2i slot0 phases p0-3, t=2i+1 slot1
// phases p4-7). Per phase: {4 ds_read_b128 A-frags (12 incl. B at q==0);
// stage ONE half-tile (2 gload_lds); s_barrier; lgkmcnt(0); setprio(1);
// 16 MFMA (quadrant q x K=64); setprio(0); [p3/p7: vmcnt(4)]; s_barrier}.
// Stage targets (FIFO-proven hazard-free, write >=1 barrier after last read):
//   p0/p1: A[2i+1]->slot1  (slot1 A last read prev p7)
//   p2/p3: B[2i+2]->slot0  (slot0 B last read p0)
//   p4/p5: A[2i+2]->slot0  (slot0 A last read p3)
//   p6/p7: B[2i+3]->slot1  (slot1 B last read p4)
// vmcnt(4) at p3 forces A[2i+1] (p0/p1) + older landed -> p4 reads safe.
// vmcnt(4) at p7 forces A[2i+2] (p4/p5) + B[2i+2] landed -> next p0 safe.
// vmcnt never drains to 0 in steady state (T4); last iteration drains.
// ---------------------------------------------------------------------------
template <bool C_BF16>
__global__ __launch_bounds__(512, 2) void gemm256p(
    const __bf16* __restrict__ A, const __bf16* __restrict__ B,
    const float* __restrict__ bias, void* __restrict__ Cv, int N, int K,
    int qcols) {
  __shared__ __bf16 As[2 * 2 * 128 * 64];  // 64 KiB
  __shared__ __bf16 Bs[2 * 2 * 128 * 64];  // 64 KiB

  const int tid = threadIdx.x;
  const int wid = tid >> 6;   // 0..7
  const int lane = tid & 63;
  const int l15 = lane & 15;
  const int quad = lane >> 4;
  const int wr = wid >> 2;    // 0..1 : M half (128 rows)
  const int wc = wid & 3;     // 0..3 : N quarter (64 cols)

  const int bn = blockIdx.x * 256;
  const int bm = blockIdx.y * 256;

  // staging: thread t -> row-in-half g*64 + (t>>3), octet (t&7) ^ (row&7)
  const int srow = tid >> 3;                      // 0..63
  const int soct = ((tid & 7) ^ (srow & 7)) * 8;  // pre-swizzled src octet
  const __bf16* gA = A + (size_t)(bm + srow) * K + soct;
  const __bf16* gB = B + (size_t)(bn + srow) * K + soct;
  __bf16* lA = As + tid * 8;  // + slot*16384 + h*8192 + g*4096 (uniform)
  __bf16* lB = Bs + tid * 8;

#define STAGE_A(h, g, ko, slot)                             \
  load_lds16(gA + (size_t)((h)*128 + (g)*64) * K + (ko),    \
             lA + (slot)*16384 + (h)*8192 + (g)*4096)
#define STAGE_B(h, g, ko, slot)                             \
  load_lds16(gB + (size_t)((h)*128 + (g)*64) * K + (ko),    \
             lB + (slot)*16384 + (h)*8192 + (g)*4096)

  // per-lane fragment read offset (row l15, k-step ksi, octet-XOR swizzle)
  int fo[2];
#pragma unroll
  for (int ksi = 0; ksi < 2; ++ksi)
    fo[ksi] = l15 * 64 + (((4 * ksi + quad) ^ (l15 & 7)) * 8);

  f32x4 acc[8][4] = {};

  // ---- prologue: A[0], B[0], B[1] (12 loads); wait tile 0 (leave B[1]) ----
  STAGE_A(0, 0, 0, 0); STAGE_A(0, 1, 0, 0);
  STAGE_A(1, 0, 0, 0); STAGE_A(1, 1, 0, 0);
  STAGE_B(0, 0, 0, 0); STAGE_B(0, 1, 0, 0);
  STAGE_B(1, 0, 0, 0); STAGE_B(1, 1, 0, 0);
  STAGE_B(0, 0, 64, 1); STAGE_B(0, 1, 64, 1);
  STAGE_B(1, 0, 64, 1); STAGE_B(1, 1, 64, 1);
  asm volatile("s_waitcnt vmcnt(4)" ::: "memory");
  asm volatile("s_barrier" ::: "memory");

  const int nit = K >> 7;  // iterations of 2 K-tiles (K=1024 -> 8)
#pragma unroll 1
  for (int i = 0; i < nit; ++i) {
    const bool more = (i + 1 < nit);
    const int ko1 = (2 * i + 1) << 6;
    const int ko2 = (2 * i + 2) << 6;
    const int ko3 = (2 * i + 3) << 6;
    bf16x8 bfr[4][2];
#pragma unroll
    for (int ts = 0; ts < 2; ++ts) {
#pragma unroll
      for (int q = 0; q < 4; ++q) {
        // ---- ds-load register subtile ----
        bf16x8 af[2][2];
#pragma unroll
        for (int j = 0; j < 2; ++j)
#pragma unroll
          for (int ksi = 0; ksi < 2; ++ksi)
            af[j][ksi] = *(const bf16x8*)(As + ts * 16384 + wr * 8192 +
                                          (2 * q + j) * 1024 + fo[ksi]);
        if (q == 0) {
#pragma unroll
          for (int nt = 0; nt < 4; ++nt)
#pragma unroll
            for (int ksi = 0; ksi < 2; ++ksi)
              bfr[nt][ksi] =
                  *(const bf16x8*)(Bs + ts * 16384 + (wc >> 1) * 8192 +
                                   (wc & 1) * 4096 + nt * 1024 + fo[ksi]);
        }
        // ---- stage one half-tile (phase p = ts*4 + q) ----
        if (ts == 0) {
          if (q == 0)      { STAGE_A(0, 0, ko1, 1); STAGE_A(0, 1, ko1, 1); }
          else if (q == 1) { STAGE_A(1, 0, ko1, 1); STAGE_A(1, 1, ko1, 1); }
          else if (q == 2) { if (more) { STAGE_B(0, 0, ko2, 0); STAGE_B(0, 1, ko2, 0); } }
          else             { if (more) { STAGE_B(1, 0, ko2, 0); STAGE_B(1, 1, ko2, 0); } }
        } else {
          if (q == 0)      { if (more) { STAGE_A(0, 0, ko2, 0); STAGE_A(0, 1, ko2, 0); } }
          else if (q == 1) { if (more) { STAGE_A(1, 0, ko2, 0); STAGE_A(1, 1, ko2, 0); } }
          else if (q == 2) { if (more) { STAGE_B(0, 0, ko3, 1); STAGE_B(0, 1, ko3, 1); } }
          else             { if (more) { STAGE_B(1, 0, ko3, 1); STAGE_B(1, 1, ko3, 1); } }
        }
        asm volatile("s_barrier" ::: "memory");
        asm volatile("s_waitcnt lgkmcnt(0)" ::: "memory");
        __builtin_amdgcn_sched_barrier(0);
        __builtin_amdgcn_s_setprio(1);
#pragma unroll
        for (int ksi = 0; ksi < 2; ++ksi)
#pragma unroll
          for (int nt = 0; nt < 4; ++nt)
#pragma unroll
            for (int j = 0; j < 2; ++j)
              acc[2 * q + j][nt] =
                  mfma16(af[j][ksi], bfr[nt][ksi], acc[2 * q + j][nt]);
        __builtin_amdgcn_s_setprio(0);
        if (q == 3) {
          if (more) asm volatile("s_waitcnt vmcnt(4)" ::: "memory");
          else      asm volatile("s_waitcnt vmcnt(0)" ::: "memory");
        }
        asm volatile("s_barrier" ::: "memory");
      }
    }
  }
#undef STAGE_A
#undef STAGE_B

  // ---- epilogue ----
  const float sc = (bn < qcols) ? 0.18033688011112043f : 1.0f;
#pragma unroll
  for (int mt = 0; mt < 8; ++mt) {
#pragma unroll
    for (int nt = 0; nt < 4; ++nt) {
      int gc = bn + wc * 64 + nt * 16 + l15;
      float bv = bias[gc];
#pragma unroll
      for (int r = 0; r < 4; ++r) {
        int gr = bm + wr * 128 + mt * 16 + quad * 4 + r;
        float val = (acc[mt][nt][r] + bv) * sc;
        if constexpr (C_BF16)
          ((__bf16*)Cv)[(size_t)gr * N + gc] = (__bf16)val;
        else
          ((float*)Cv)[(size_t)gr * N + gc] = val;
      }
    }
  }
}

// ---------------------------------------------------------------------------
// Proven round-0 128x128 GEMM (m97 structure + chunk swizzle) for out-proj.
// ---------------------------------------------------------------------------
template <bool C_BF16>
__global__ __launch_bounds__(256) void gemm_bt(
    const __bf16* __restrict__ A, const __bf16* __restrict__ B,
    const float* __restrict__ bias, void* __restrict__ Cv, int M, int N,
    int K, int qcols) {
  __shared__ __bf16 As[2][128 * 32];
  __shared__ __bf16 Bs[2][128 * 32];

  const int tid = threadIdx.x;
  const int wid = tid >> 6;
  const int lane = tid & 63;
  const int l15 = lane & 15;
  const int quad = lane >> 4;
  const int bm = blockIdx.y * 128;
  const int bn = blockIdx.x * 128;
  const int wm = (wid & 1) * 64;
  const int wn = (wid >> 1) * 64;

  const int srow = wid * 16 + (lane >> 2);
  const int schunk = ((lane & 3) ^ ((lane >> 3) & 3)) * 8;
  const __bf16* gA = A + (size_t)(bm + srow) * K + schunk;
  const __bf16* gB = B + (size_t)(bn + srow) * K + schunk;
  const int ldsoff = wid * 16 * 32;  // wave-uniform

  const int fsl = (quad ^ ((l15 >> 1) & 3)) * 8;

  f32x4 acc[4][4] = {};

  load_lds16(gA, &As[0][ldsoff]);
  load_lds16(gA + (size_t)64 * K, &As[0][64 * 32 + ldsoff]);
  load_lds16(gB, &Bs[0][ldsoff]);
  load_lds16(gB + (size_t)64 * K, &Bs[0][64 * 32 + ldsoff]);

  const int niter = K >> 5;
  for (int it = 0; it < niter; ++it) {
    const int cur = it & 1;
    __syncthreads();
    if (it + 1 < niter) {
      int k0 = (it + 1) << 5;
      load_lds16(gA + k0, &As[1 - cur][ldsoff]);
      load_lds16(gA + k0 + (size_t)64 * K, &As[1 - cur][64 * 32 + ldsoff]);
      load_lds16(gB + k0, &Bs[1 - cur][ldsoff]);
      load_lds16(gB + k0 + (size_t)64 * K, &Bs[1 - cur][64 * 32 + ldsoff]);
    }
    bf16x8 af[4], bf[4];
#pragma unroll
    for (int i = 0; i < 4; ++i)
      af[i] = *(const bf16x8*)(&As[cur][(wm + i * 16 + l15) * 32 + fsl]);
#pragma unroll
    for (int i = 0; i < 4; ++i)
      bf[i] = *(const bf16x8*)(&Bs[cur][(wn + i * 16 + l15) * 32 + fsl]);
#pragma unroll
    for (int mt = 0; mt < 4; ++mt)
#pragma unroll
      for (int nt = 0; nt < 4; ++nt)
        acc[mt][nt] = mfma16(af[mt], bf[nt], acc[mt][nt]);
  }

  const float sc = (bn < qcols) ? 0.18033688011112043f : 1.0f;
#pragma unroll
  for (int mt = 0; mt < 4; ++mt) {
#pragma unroll
    for (int nt = 0; nt < 4; ++nt) {
      int gc = bn + wn + nt * 16 + l15;
      float bv = bias[gc];
#pragma unroll
      for (int r = 0; r < 4; ++r) {
        int gr = bm + wm + mt * 16 + quad * 4 + r;
        float val = (acc[mt][nt][r] + bv) * sc;
        if constexpr (C_BF16)
          ((__bf16*)Cv)[(size_t)gr * N + gc] = (__bf16)val;
        else
          ((float*)Cv)[(size_t)gr * N + gc] = val;
      }
    }
  }
}

// exp + (optional causal mask) + deferred-l + packed P store in pi-layout.
template <bool MASK>
__device__ __forceinline__ void softmax_block(f32x4 (&s)[2][4],
                                              float (&lsum)[2][4],
                                              __bf16* __restrict__ psw,
                                              int kv0, int qrow_base, int quad,
                                              int l15) {
#pragma unroll
  for (int mt = 0; mt < 2; ++mt) {
#pragma unroll
    for (int r = 0; r < 4; ++r) {
      int prow = mt * 16 + quad * 4 + r;
      float p[4];
#pragma unroll
      for (int nt = 0; nt < 4; ++nt) {
        p[nt] = fast_exp2(s[mt][nt][r]);  // scale pre-folded into Q
        if constexpr (MASK) {
          if ((kv0 + nt * 16 + l15) > (qrow_base + prow)) p[nt] = 0.f;
        }
      }
      lsum[mt][r] += (p[0] + p[1]) + (p[2] + p[3]);
      uint2 w = {pack_bf16(p[0], p[1]), pack_bf16(p[2], p[3])};
      int o = ((l15 >> 1) ^ (prow & 7)) & 7;
      *(uint2*)(psw + prow * 64 + o * 8 + 4 * (l15 & 1)) = w;
    }
  }
}

// Flash attention, causal. qkv: (B*T, 3072) bf16 (Q pre-scaled by log2e/8);
// out: (B*T, 1024) bf16. Grid (64 bh, 8 pb) bh-fastest (KV L2-resident per
// XCD). Block 256 = 4 waves, BQ=128, BKV=64; phases {pb, 15-pb} -> 34 iters.
// P/V k-index permuted by pi(k)=4*(k&15)+(k>>4) -> packed P stores; XOR
// octet swizzles keep LDS bank-uniform. No-max softmax, deferred l.
// All LDS fragment offsets precomputed outside the kv-loop.
__global__ __launch_bounds__(256) void attn_kernel(
    const __bf16* __restrict__ qkv, __bf16* __restrict__ out) {
  constexpr int T = 2048, C3 = 3072;
  constexpr int KVSTEP = 64 * C3;
  __shared__ __bf16 Ks[2][64 * 64];  // [kv][d]
  __shared__ __bf16 Vt[2][64 * 64];  // [d][pi(kv)]
  __shared__ __bf16 Ps[4][32 * 64];  // per-wave [qrow][pi(kv)]

  const int tid = threadIdx.x;
  const int wid = tid >> 6;
  const int lane = tid & 63;
  const int l15 = lane & 15;
  const int quad = lane >> 4;
  const int bh = blockIdx.x;  // 0..63 (fastest -> same XCD per bh)
  const int pb = blockIdx.y;  // 0..7
  const int b = bh >> 4, h = bh & 15;
  const size_t rowbase = (size_t)b * T;

  const int kr = tid >> 3;  // K staging: rows kr, kr+32
  const int kc = tid & 7;   // d-octet
  const int vj = tid >> 4;  // V staging: rows vj+16i -> pi-cols 4vj+i
  const int vn = tid & 15;  // d-nibble

  const __bf16* gk_base = qkv + rowbase * C3 + 1024 + h * 64 + kr * C3 + kc * 8;
  const __bf16* gv_base = qkv + rowbase * C3 + 2048 + h * 64 + vj * C3 + vn * 4;

  // ---- loop-invariant LDS offsets (elements) ----
  int ks_st0 = kr * 64 + ((kc ^ (kr & 7)) * 8);            // K store row kr
  int ks_st1 = (kr + 32) * 64 + ((kc ^ ((kr + 32) & 7)) * 8);
  int vt_st[4];
#pragma unroll
  for (int dd = 0; dd < 4; ++dd) {
    int d = 4 * vn + dd;
    vt_st[dd] = d * 64 + ((((vj >> 1) ^ (d & 7) ^ (d >> 3)) & 7) * 8) +
                4 * (vj & 1);
  }
  int kf_off[4][2];
#pragma unroll
  for (int nt = 0; nt < 4; ++nt)
#pragma unroll
    for (int ksi = 0; ksi < 2; ++ksi)
      kf_off[nt][ksi] =
          (nt * 16 + l15) * 64 + (((4 * ksi + quad) ^ (l15 & 7)) * 8);
  int pf_off[2][2];
#pragma unroll
  for (int mt = 0; mt < 2; ++mt)
#pragma unroll
    for (int ksi = 0; ksi < 2; ++ksi)
      pf_off[mt][ksi] =
          (mt * 16 + l15) * 64 + (((4 * ksi + quad) ^ (l15 & 7)) * 8);
  int vf_off[4][2];
#pragma unroll
  for (int ntv = 0; ntv < 4; ++ntv)
#pragma unroll
    for (int ksi = 0; ksi < 2; ++ksi) {
      int d = ntv * 16 + l15;
      vf_off[ntv][ksi] =
          d * 64 + ((((4 * ksi + quad) ^ (d & 7) ^ (d >> 3)) & 7) * 8);
    }

#pragma unroll 1
  for (int phase = 0; phase < 2; ++phase) {
    const int qp = phase == 0 ? pb : 15 - pb;
    const int q0 = qp * 128;
    const int ntiles = 2 * qp + 2;
    const int qrow_base = q0 + wid * 32;

    bf16x8 qf[2][2];
#pragma unroll
    for (int mt = 0; mt < 2; ++mt)
#pragma unroll
      for (int ksi = 0; ksi < 2; ++ksi)
        qf[mt][ksi] = *(const bf16x8*)(
            qkv + (rowbase + qrow_base + mt * 16 + l15) * C3 + h * 64 +
            ksi * 32 + quad * 8);

    f32x4 acc[2][4] = {};
    float lsum[2][4] = {};

    const __bf16* gk = gk_base;
    const __bf16* gv = gv_base;

    bf16x8 kreg[2];
    bf16x4 vreg[4];
    kreg[0] = *(const bf16x8*)(gk);
    kreg[1] = *(const bf16x8*)(gk + 32 * C3);
#pragma unroll
    for (int i = 0; i < 4; ++i)
      vreg[i] = *(const bf16x4*)(gv + i * 16 * C3);

    __syncthreads();  // previous phase's readers done

    for (int j = 0; j < ntiles; ++j) {
      __bf16* ksb = Ks[j & 1];
      __bf16* vtb = Vt[j & 1];
      *(bf16x8*)(ksb + ks_st0) = kreg[0];
      *(bf16x8*)(ksb + ks_st1) = kreg[1];
#pragma unroll
      for (int dd = 0; dd < 4; ++dd) {
        bf16x4 t = {vreg[0][dd], vreg[1][dd], vreg[2][dd], vreg[3][dd]};
        *(bf16x4*)(vtb + vt_st[dd]) = t;
      }
      if (j + 1 < ntiles) {
        gk += KVSTEP;
        gv += KVSTEP;
        kreg[0] = *(const bf16x8*)(gk);
        kreg[1] = *(const bf16x8*)(gk + 32 * C3);
#pragma unroll
        for (int i = 0; i < 4; ++i)
          vreg[i] = *(const bf16x4*)(gv + i * 16 * C3);
      }
      __syncthreads();

      const int kv0 = j * 64;
      // ---- S = Q K^T ----
      f32x4 s[2][4] = {};
#pragma unroll
      for (int nt = 0; nt < 4; ++nt) {
#pragma unroll
        for (int ksi = 0; ksi < 2; ++ksi) {
          bf16x8 kf = *(const bf16x8*)(ksb + kf_off[nt][ksi]);
#pragma unroll
          for (int mt = 0; mt < 2; ++mt)
            s[mt][nt] = mfma16(qf[mt][ksi], kf, s[mt][nt]);
        }
      }
      // ---- softmax (wave-uniform mask branch) ----
      if ((kv0 + 63) > qrow_base)
        softmax_block<true>(s, lsum, Ps[wid], kv0, qrow_base, quad, l15);
      else
        softmax_block<false>(s, lsum, Ps[wid], kv0, qrow_base, quad, l15);

      // ---- O += P V (per-wave Ps: no barrier) ----
#pragma unroll
      for (int ksi = 0; ksi < 2; ++ksi) {
        bf16x8 pf[2];
#pragma unroll
        for (int mt = 0; mt < 2; ++mt)
          pf[mt] = *(const bf16x8*)(Ps[wid] + pf_off[mt][ksi]);
#pragma unroll
        for (int ntv = 0; ntv < 4; ++ntv) {
          bf16x8 vf = *(const bf16x8*)(vtb + vf_off[ntv][ksi]);
#pragma unroll
          for (int mt = 0; mt < 2; ++mt)
            acc[mt][ntv] = mfma16(pf[mt], vf, acc[mt][ntv]);
        }
      }
    }

    // ---- phase epilogue: reduce l, normalize, store ----
#pragma unroll
    for (int mt = 0; mt < 2; ++mt)
#pragma unroll
      for (int r = 0; r < 4; ++r) {
        float l = lsum[mt][r];
        l += __shfl_xor(l, 1);
        l += __shfl_xor(l, 2);
        l += __shfl_xor(l, 4);
        l += __shfl_xor(l, 8);
        float inv = 1.0f / l;
        int row = qrow_base + mt * 16 + quad * 4 + r;
        size_t ob = (rowbase + row) * 1024 + h * 64;
#pragma unroll
        for (int ntv = 0; ntv < 4; ++ntv)
          out[ob + ntv * 16 + l15] = (__bf16)(acc[mt][ntv][r] * inv);
      }
  }
}

extern "C" void kernel_launch(void* const* d_in, const int* in_sizes, int n_in,
                              void* d_out, int out_size, void* d_ws,
                              size_t ws_size, hipStream_t stream) {
  const float* x = (const float*)d_in[0];
  const float* qkv_w = (const float*)d_in[1];
  const float* qkv_b = (const float*)d_in[2];
  const float* out_w = (const float*)d_in[3];
  const float* out_b = (const float*)d_in[4];
  float* out = (float*)d_out;

  __bf16* qkv_ws = (__bf16*)d_ws;                  // 8192*3072
  __bf16* attn_ws = qkv_ws + (size_t)8192 * 3072;  // 8192*1024
  __bf16* xb = attn_ws + (size_t)8192 * 1024;      // 8192*1024
  __bf16* wqb = xb + (size_t)8192 * 1024;          // 3072*1024
  __bf16* wob = wqb + (size_t)3072 * 1024;         // 1024*1024

  convert3<<<6144, 256, 0, stream>>>(x, qkv_w, out_w, xb, wqb, wob);
  // QKV: M=8192, N=3072 -> 256^2 tiles, grid 12x32 = 384 blocks
  gemm256p<true><<<dim3(12, 32), 512, 0, stream>>>(xb, wqb, qkv_b, qkv_ws,
                                                   3072, 1024, 1024);
  attn_kernel<<<dim3(64, 8), 256, 0, stream>>>(qkv_ws, attn_ws);
  // out-proj: proven 128^2 kernel, grid 8x64 = 512 blocks
  gemm_bt<false><<<dim3(8, 64), 256, 0, stream>>>(attn_ws, wob, out_b, out,
                                                  8192, 1024, 1024, 0);
}

// Round 3
// 247.820 us; speedup vs baseline: 1.0148x; 1.0148x over previous
//
#include <hip/hip_runtime.h>

typedef __bf16 bf16x8 __attribute__((ext_vector_type(8)));
typedef __bf16 bf16x4 __attribute__((ext_vector_type(4)));
typedef float f32x4 __attribute__((ext_vector_type(4)));

typedef const __attribute__((address_space(1))) void* gptr_t;
typedef __attribute__((address_space(3))) void* lptr_t;

__device__ __forceinline__ f32x4 mfma16(bf16x8 a, bf16x8 b, f32x4 c) {
  return __builtin_amdgcn_mfma_f32_16x16x32_bf16(a, b, c, 0, 0, 0);
}

__device__ __forceinline__ void load_lds16(const __bf16* g, __bf16* l) {
  __builtin_amdgcn_global_load_lds((gptr_t)g, (lptr_t)l, 16, 0, 0);
}

__device__ __forceinline__ float fast_exp2(float x) {
#if __has_builtin(__builtin_amdgcn_exp2f)
  return __builtin_amdgcn_exp2f(x);  // raw v_exp_f32
#else
  return exp2f(x);
#endif
}

// round-to-nearest(+away) f32->bf16 for two values, packed into one dword
__device__ __forceinline__ unsigned pack_bf16(float f0, float f1) {
  unsigned u0 = __builtin_bit_cast(unsigned, f0) + 0x8000u;
  unsigned u1 = __builtin_bit_cast(unsigned, f1) + 0x8000u;
  return __builtin_amdgcn_perm(u1, u0, 0x07060302);
}

// ---- fp32 -> bf16 pre-convert: x (4096 blks), qkv_w (1536), out_w (512) ----
__global__ __launch_bounds__(256) void convert3(
    const float* __restrict__ x, const float* __restrict__ w1,
    const float* __restrict__ w2, __bf16* __restrict__ xb,
    __bf16* __restrict__ w1b, __bf16* __restrict__ w2b) {
  int bid = blockIdx.x;
  const float* src;
  __bf16* dst;
  int base;
  if (bid < 4096) {
    src = x; dst = xb; base = bid;
  } else if (bid < 5632) {
    src = w1; dst = w1b; base = bid - 4096;
  } else {
    src = w2; dst = w2b; base = bid - 5632;
  }
  size_t off = (size_t)base * 2048 + threadIdx.x * 8;
  float4 v0 = *(const float4*)(src + off);
  float4 v1 = *(const float4*)(src + off + 4);
  bf16x8 o = {(__bf16)v0.x, (__bf16)v0.y, (__bf16)v0.z, (__bf16)v0.w,
              (__bf16)v1.x, (__bf16)v1.y, (__bf16)v1.z, (__bf16)v1.w};
  *(bf16x8*)(dst + off) = o;
}

// ---------------------------------------------------------------------------
// 256x256 8-phase pipelined GEMM (m201 template port, plain HIP).
// C[M][N] = A[M][K] @ B[N][K]^T + bias[N].
// 8 waves (2M x 4N), per-wave 128x64 output, BK=64, LDS 128 KiB.
// R3 change: NO explicit lgkmcnt(0)/sched_barrier before the MFMA cluster.
// The ds_reads are compiler-emitted loads; the compiler interleaves
// fine-grained lgkmcnt waits with the MFMAs (m97 disasm evidence), so the
// LDS drain (~350-1000 cyc/phase) overlaps the MFMA cluster (~515 cyc)
// instead of serializing with it (r2: 1400 cyc phases = 515+850 serial).
// Safety: every ds_read is consumed before the closing barrier, so
// compiler dependency-waits already guarantee completion before any other
// wave can overwrite the region. vmcnt FIFO identical to r2 (HW-passed):
//   p0/p1: A[2i+1]->slot1   p2/p3: B[2i+2]->slot0
//   p4/p5: A[2i+2]->slot0   p6/p7: B[2i+3]->slot1
//   vmcnt(4) at p3/p7 (counted, never 0 in steady state); drain at end.
// Octet-XOR swizzle: LDS position p of row r holds global octet p^(r&7);
// fragment read at octet (4*ksi+quad)^(l15&7). Linear LDS dest +
// pre-swizzled global source (rule #21). Bank conflicts = 0 (measured).
// ---------------------------------------------------------------------------
template <bool C_BF16>
__global__ __launch_bounds__(512, 2) void gemm256p(
    const __bf16* __restrict__ A, const __bf16* __restrict__ B,
    const float* __restrict__ bias, void* __restrict__ Cv, int N, int K,
    int qcols) {
  __shared__ __bf16 As[2 * 2 * 128 * 64];  // 64 KiB
  __shared__ __bf16 Bs[2 * 2 * 128 * 64];  // 64 KiB

  const int tid = threadIdx.x;
  const int wid = tid >> 6;   // 0..7
  const int lane = tid & 63;
  const int l15 = lane & 15;
  const int quad = lane >> 4;
  const int wr = wid >> 2;    // 0..1 : M half (128 rows)
  const int wc = wid & 3;     // 0..3 : N quarter (64 cols)

  const int bn = blockIdx.x * 256;
  const int bm = blockIdx.y * 256;

  // staging: thread t -> row-in-half g*64 + (t>>3), octet (t&7) ^ (row&7)
  const int srow = tid >> 3;                      // 0..63
  const int soct = ((tid & 7) ^ (srow & 7)) * 8;  // pre-swizzled src octet
  const __bf16* gA = A + (size_t)(bm + srow) * K + soct;
  const __bf16* gB = B + (size_t)(bn + srow) * K + soct;
  __bf16* lA = As + tid * 8;  // + slot*16384 + h*8192 + g*4096 (uniform)
  __bf16* lB = Bs + tid * 8;

#define STAGE_A(h, g, ko, slot)                             \
  load_lds16(gA + (size_t)((h)*128 + (g)*64) * K + (ko),    \
             lA + (slot)*16384 + (h)*8192 + (g)*4096)
#define STAGE_B(h, g, ko, slot)                             \
  load_lds16(gB + (size_t)((h)*128 + (g)*64) * K + (ko),    \
             lB + (slot)*16384 + (h)*8192 + (g)*4096)

  // per-lane fragment read offset (row l15, k-step ksi, octet-XOR swizzle)
  int fo[2];
#pragma unroll
  for (int ksi = 0; ksi < 2; ++ksi)
    fo[ksi] = l15 * 64 + (((4 * ksi + quad) ^ (l15 & 7)) * 8);

  f32x4 acc[8][4] = {};

  // ---- prologue: A[0], B[0], B[1] (12 loads); wait tile 0 (leave B[1]) ----
  STAGE_A(0, 0, 0, 0); STAGE_A(0, 1, 0, 0);
  STAGE_A(1, 0, 0, 0); STAGE_A(1, 1, 0, 0);
  STAGE_B(0, 0, 0, 0); STAGE_B(0, 1, 0, 0);
  STAGE_B(1, 0, 0, 0); STAGE_B(1, 1, 0, 0);
  STAGE_B(0, 0, 64, 1); STAGE_B(0, 1, 64, 1);
  STAGE_B(1, 0, 64, 1); STAGE_B(1, 1, 64, 1);
  asm volatile("s_waitcnt vmcnt(4)" ::: "memory");
  asm volatile("s_barrier" ::: "memory");

  const int nit = K >> 7;  // iterations of 2 K-tiles (K=1024 -> 8)
#pragma unroll 1
  for (int i = 0; i < nit; ++i) {
    const bool more = (i + 1 < nit);
    const int ko1 = (2 * i + 1) << 6;
    const int ko2 = (2 * i + 2) << 6;
    const int ko3 = (2 * i + 3) << 6;
    bf16x8 bfr[4][2];
#pragma unroll
    for (int ts = 0; ts < 2; ++ts) {
#pragma unroll
      for (int q = 0; q < 4; ++q) {
        // ---- ds-load register subtile ----
        bf16x8 af[2][2];
#pragma unroll
        for (int j = 0; j < 2; ++j)
#pragma unroll
          for (int ksi = 0; ksi < 2; ++ksi)
            af[j][ksi] = *(const bf16x8*)(As + ts * 16384 + wr * 8192 +
                                          (2 * q + j) * 1024 + fo[ksi]);
        if (q == 0) {
#pragma unroll
          for (int nt = 0; nt < 4; ++nt)
#pragma unroll
            for (int ksi = 0; ksi < 2; ++ksi)
              bfr[nt][ksi] =
                  *(const bf16x8*)(Bs + ts * 16384 + (wc >> 1) * 8192 +
                                   (wc & 1) * 4096 + nt * 1024 + fo[ksi]);
        }
        // ---- stage one half-tile (phase p = ts*4 + q) ----
        if (ts == 0) {
          if (q == 0)      { STAGE_A(0, 0, ko1, 1); STAGE_A(0, 1, ko1, 1); }
          else if (q == 1) { STAGE_A(1, 0, ko1, 1); STAGE_A(1, 1, ko1, 1); }
          else if (q == 2) { if (more) { STAGE_B(0, 0, ko2, 0); STAGE_B(0, 1, ko2, 0); } }
          else             { if (more) { STAGE_B(1, 0, ko2, 0); STAGE_B(1, 1, ko2, 0); } }
        } else {
          if (q == 0)      { if (more) { STAGE_A(0, 0, ko2, 0); STAGE_A(0, 1, ko2, 0); } }
          else if (q == 1) { if (more) { STAGE_A(1, 0, ko2, 0); STAGE_A(1, 1, ko2, 0); } }
          else if (q == 2) { if (more) { STAGE_B(0, 0, ko3, 1); STAGE_B(0, 1, ko3, 1); } }
          else             { if (more) { STAGE_B(1, 0, ko3, 1); STAGE_B(1, 1, ko3, 1); } }
        }
        asm volatile("s_barrier" ::: "memory");
        // NOTE: no lgkmcnt(0)/sched_barrier here (r3 change) — compiler
        // interleaves its own counted lgkm waits with the MFMA cluster.
        __builtin_amdgcn_s_setprio(1);
#pragma unroll
        for (int ksi = 0; ksi < 2; ++ksi)
#pragma unroll
          for (int nt = 0; nt < 4; ++nt)
#pragma unroll
            for (int j = 0; j < 2; ++j)
              acc[2 * q + j][nt] =
                  mfma16(af[j][ksi], bfr[nt][ksi], acc[2 * q + j][nt]);
        __builtin_amdgcn_s_setprio(0);
        if (q == 3) {
          if (more) asm volatile("s_waitcnt vmcnt(4)" ::: "memory");
          else      asm volatile("s_waitcnt vmcnt(0)" ::: "memory");
        }
        asm volatile("s_barrier" ::: "memory");
      }
    }
  }
#undef STAGE_A
#undef STAGE_B

  // ---- epilogue ----
  const float sc = (bn < qcols) ? 0.18033688011112043f : 1.0f;
#pragma unroll
  for (int mt = 0; mt < 8; ++mt) {
#pragma unroll
    for (int nt = 0; nt < 4; ++nt) {
      int gc = bn + wc * 64 + nt * 16 + l15;
      float bv = bias[gc];
#pragma unroll
      for (int r = 0; r < 4; ++r) {
        int gr = bm + wr * 128 + mt * 16 + quad * 4 + r;
        float val = (acc[mt][nt][r] + bv) * sc;
        if constexpr (C_BF16)
          ((__bf16*)Cv)[(size_t)gr * N + gc] = (__bf16)val;
        else
          ((float*)Cv)[(size_t)gr * N + gc] = val;
      }
    }
  }
}

// ---------------------------------------------------------------------------
// Proven round-0 128x128 GEMM (m97 structure + chunk swizzle) for out-proj.
// ---------------------------------------------------------------------------
template <bool C_BF16>
__global__ __launch_bounds__(256) void gemm_bt(
    const __bf16* __restrict__ A, const __bf16* __restrict__ B,
    const float* __restrict__ bias, void* __restrict__ Cv, int M, int N,
    int K, int qcols) {
  __shared__ __bf16 As[2][128 * 32];
  __shared__ __bf16 Bs[2][128 * 32];

  const int tid = threadIdx.x;
  const int wid = tid >> 6;
  const int lane = tid & 63;
  const int l15 = lane & 15;
  const int quad = lane >> 4;
  const int bm = blockIdx.y * 128;
  const int bn = blockIdx.x * 128;
  const int wm = (wid & 1) * 64;
  const int wn = (wid >> 1) * 64;

  const int srow = wid * 16 + (lane >> 2);
  const int schunk = ((lane & 3) ^ ((lane >> 3) & 3)) * 8;
  const __bf16* gA = A + (size_t)(bm + srow) * K + schunk;
  const __bf16* gB = B + (size_t)(bn + srow) * K + schunk;
  const int ldsoff = wid * 16 * 32;  // wave-uniform

  const int fsl = (quad ^ ((l15 >> 1) & 3)) * 8;

  f32x4 acc[4][4] = {};

  load_lds16(gA, &As[0][ldsoff]);
  load_lds16(gA + (size_t)64 * K, &As[0][64 * 32 + ldsoff]);
  load_lds16(gB, &Bs[0][ldsoff]);
  load_lds16(gB + (size_t)64 * K, &Bs[0][64 * 32 + ldsoff]);

  const int niter = K >> 5;
  for (int it = 0; it < niter; ++it) {
    const int cur = it & 1;
    __syncthreads();
    if (it + 1 < niter) {
      int k0 = (it + 1) << 5;
      load_lds16(gA + k0, &As[1 - cur][ldsoff]);
      load_lds16(gA + k0 + (size_t)64 * K, &As[1 - cur][64 * 32 + ldsoff]);
      load_lds16(gB + k0, &Bs[1 - cur][ldsoff]);
      load_lds16(gB + k0 + (size_t)64 * K, &Bs[1 - cur][64 * 32 + ldsoff]);
    }
    bf16x8 af[4], bf[4];
#pragma unroll
    for (int i = 0; i < 4; ++i)
      af[i] = *(const bf16x8*)(&As[cur][(wm + i * 16 + l15) * 32 + fsl]);
#pragma unroll
    for (int i = 0; i < 4; ++i)
      bf[i] = *(const bf16x8*)(&Bs[cur][(wn + i * 16 + l15) * 32 + fsl]);
#pragma unroll
    for (int mt = 0; mt < 4; ++mt)
#pragma unroll
      for (int nt = 0; nt < 4; ++nt)
        acc[mt][nt] = mfma16(af[mt], bf[nt], acc[mt][nt]);
  }

  const float sc = (bn < qcols) ? 0.18033688011112043f : 1.0f;
#pragma unroll
  for (int mt = 0; mt < 4; ++mt) {
#pragma unroll
    for (int nt = 0; nt < 4; ++nt) {
      int gc = bn + wn + nt * 16 + l15;
      float bv = bias[gc];
#pragma unroll
      for (int r = 0; r < 4; ++r) {
        int gr = bm + wm + mt * 16 + quad * 4 + r;
        float val = (acc[mt][nt][r] + bv) * sc;
        if constexpr (C_BF16)
          ((__bf16*)Cv)[(size_t)gr * N + gc] = (__bf16)val;
        else
          ((float*)Cv)[(size_t)gr * N + gc] = val;
      }
    }
  }
}

// exp + (optional causal mask) + deferred-l + packed P store in pi-layout.
template <bool MASK>
__device__ __forceinline__ void softmax_block(f32x4 (&s)[2][4],
                                              float (&lsum)[2][4],
                                              __bf16* __restrict__ psw,
                                              int kv0, int qrow_base, int quad,
                                              int l15) {
#pragma unroll
  for (int mt = 0; mt < 2; ++mt) {
#pragma unroll
    for (int r = 0; r < 4; ++r) {
      int prow = mt * 16 + quad * 4 + r;
      float p[4];
#pragma unroll
      for (int nt = 0; nt < 4; ++nt) {
        p[nt] = fast_exp2(s[mt][nt][r]);  // scale pre-folded into Q
        if constexpr (MASK) {
          if ((kv0 + nt * 16 + l15) > (qrow_base + prow)) p[nt] = 0.f;
        }
      }
      lsum[mt][r] += (p[0] + p[1]) + (p[2] + p[3]);
      uint2 w = {pack_bf16(p[0], p[1]), pack_bf16(p[2], p[3])};
      int o = ((l15 >> 1) ^ (prow & 7)) & 7;
      *(uint2*)(psw + prow * 64 + o * 8 + 4 * (l15 & 1)) = w;
    }
  }
}

// Flash attention, causal. qkv: (B*T, 3072) bf16 (Q pre-scaled by log2e/8);
// out: (B*T, 1024) bf16. Grid (64 bh, 8 pb) bh-fastest (KV L2-resident per
// XCD). Block 256 = 4 waves, BQ=128, BKV=64; phases {pb, 15-pb} -> 34 iters.
// P/V k-index permuted by pi(k)=4*(k&15)+(k>>4) -> packed P stores; XOR
// octet swizzles keep LDS bank-uniform. No-max softmax, deferred l.
// All LDS fragment offsets precomputed outside the kv-loop.
__global__ __launch_bounds__(256) void attn_kernel(
    const __bf16* __restrict__ qkv, __bf16* __restrict__ out) {
  constexpr int T = 2048, C3 = 3072;
  constexpr int KVSTEP = 64 * C3;
  __shared__ __bf16 Ks[2][64 * 64];  // [kv][d]
  __shared__ __bf16 Vt[2][64 * 64];  // [d][pi(kv)]
  __shared__ __bf16 Ps[4][32 * 64];  // per-wave [qrow][pi(kv)]

  const int tid = threadIdx.x;
  const int wid = tid >> 6;
  const int lane = tid & 63;
  const int l15 = lane & 15;
  const int quad = lane >> 4;
  const int bh = blockIdx.x;  // 0..63 (fastest -> same XCD per bh)
  const int pb = blockIdx.y;  // 0..7
  const int b = bh >> 4, h = bh & 15;
  const size_t rowbase = (size_t)b * T;

  const int kr = tid >> 3;  // K staging: rows kr, kr+32
  const int kc = tid & 7;   // d-octet
  const int vj = tid >> 4;  // V staging: rows vj+16i -> pi-cols 4vj+i
  const int vn = tid & 15;  // d-nibble

  const __bf16* gk_base = qkv + rowbase * C3 + 1024 + h * 64 + kr * C3 + kc * 8;
  const __bf16* gv_base = qkv + rowbase * C3 + 2048 + h * 64 + vj * C3 + vn * 4;

  // ---- loop-invariant LDS offsets (elements) ----
  int ks_st0 = kr * 64 + ((kc ^ (kr & 7)) * 8);            // K store row kr
  int ks_st1 = (kr + 32) * 64 + ((kc ^ ((kr + 32) & 7)) * 8);
  int vt_st[4];
#pragma unroll
  for (int dd = 0; dd < 4; ++dd) {
    int d = 4 * vn + dd;
    vt_st[dd] = d * 64 + ((((vj >> 1) ^ (d & 7) ^ (d >> 3)) & 7) * 8) +
                4 * (vj & 1);
  }
  int kf_off[4][2];
#pragma unroll
  for (int nt = 0; nt < 4; ++nt)
#pragma unroll
    for (int ksi = 0; ksi < 2; ++ksi)
      kf_off[nt][ksi] =
          (nt * 16 + l15) * 64 + (((4 * ksi + quad) ^ (l15 & 7)) * 8);
  int pf_off[2][2];
#pragma unroll
  for (int mt = 0; mt < 2; ++mt)
#pragma unroll
    for (int ksi = 0; ksi < 2; ++ksi)
      pf_off[mt][ksi] =
          (mt * 16 + l15) * 64 + (((4 * ksi + quad) ^ (l15 & 7)) * 8);
  int vf_off[4][2];
#pragma unroll
  for (int ntv = 0; ntv < 4; ++ntv)
#pragma unroll
    for (int ksi = 0; ksi < 2; ++ksi) {
      int d = ntv * 16 + l15;
      vf_off[ntv][ksi] =
          d * 64 + ((((4 * ksi + quad) ^ (d & 7) ^ (d >> 3)) & 7) * 8);
    }

#pragma unroll 1
  for (int phase = 0; phase < 2; ++phase) {
    const int qp = phase == 0 ? pb : 15 - pb;
    const int q0 = qp * 128;
    const int ntiles = 2 * qp + 2;
    const int qrow_base = q0 + wid * 32;

    bf16x8 qf[2][2];
#pragma unroll
    for (int mt = 0; mt < 2; ++mt)
#pragma unroll
      for (int ksi = 0; ksi < 2; ++ksi)
        qf[mt][ksi] = *(const bf16x8*)(
            qkv + (rowbase + qrow_base + mt * 16 + l15) * C3 + h * 64 +
            ksi * 32 + quad * 8);

    f32x4 acc[2][4] = {};
    float lsum[2][4] = {};

    const __bf16* gk = gk_base;
    const __bf16* gv = gv_base;

    bf16x8 kreg[2];
    bf16x4 vreg[4];
    kreg[0] = *(const bf16x8*)(gk);
    kreg[1] = *(const bf16x8*)(gk + 32 * C3);
#pragma unroll
    for (int i = 0; i < 4; ++i)
      vreg[i] = *(const bf16x4*)(gv + i * 16 * C3);

    __syncthreads();  // previous phase's readers done

    for (int j = 0; j < ntiles; ++j) {
      __bf16* ksb = Ks[j & 1];
      __bf16* vtb = Vt[j & 1];
      *(bf16x8*)(ksb + ks_st0) = kreg[0];
      *(bf16x8*)(ksb + ks_st1) = kreg[1];
#pragma unroll
      for (int dd = 0; dd < 4; ++dd) {
        bf16x4 t = {vreg[0][dd], vreg[1][dd], vreg[2][dd], vreg[3][dd]};
        *(bf16x4*)(vtb + vt_st[dd]) = t;
      }
      if (j + 1 < ntiles) {
        gk += KVSTEP;
        gv += KVSTEP;
        kreg[0] = *(const bf16x8*)(gk);
        kreg[1] = *(const bf16x8*)(gk + 32 * C3);
#pragma unroll
        for (int i = 0; i < 4; ++i)
          vreg[i] = *(const bf16x4*)(gv + i * 16 * C3);
      }
      __syncthreads();

      const int kv0 = j * 64;
      // ---- S = Q K^T ----
      f32x4 s[2][4] = {};
#pragma unroll
      for (int nt = 0; nt < 4; ++nt) {
#pragma unroll
        for (int ksi = 0; ksi < 2; ++ksi) {
          bf16x8 kf = *(const bf16x8*)(ksb + kf_off[nt][ksi]);
#pragma unroll
          for (int mt = 0; mt < 2; ++mt)
            s[mt][nt] = mfma16(qf[mt][ksi], kf, s[mt][nt]);
        }
      }
      // ---- softmax (wave-uniform mask branch) ----
      if ((kv0 + 63) > qrow_base)
        softmax_block<true>(s, lsum, Ps[wid], kv0, qrow_base, quad, l15);
      else
        softmax_block<false>(s, lsum, Ps[wid], kv0, qrow_base, quad, l15);

      // ---- O += P V (per-wave Ps: no barrier) ----
#pragma unroll
      for (int ksi = 0; ksi < 2; ++ksi) {
        bf16x8 pf[2];
#pragma unroll
        for (int mt = 0; mt < 2; ++mt)
          pf[mt] = *(const bf16x8*)(Ps[wid] + pf_off[mt][ksi]);
#pragma unroll
        for (int ntv = 0; ntv < 4; ++ntv) {
          bf16x8 vf = *(const bf16x8*)(vtb + vf_off[ntv][ksi]);
#pragma unroll
          for (int mt = 0; mt < 2; ++mt)
            acc[mt][ntv] = mfma16(pf[mt], vf, acc[mt][ntv]);
        }
      }
    }

    // ---- phase epilogue: reduce l, normalize, store ----
#pragma unroll
    for (int mt = 0; mt < 2; ++mt)
#pragma unroll
      for (int r = 0; r < 4; ++r) {
        float l = lsum[mt][r];
        l += __shfl_xor(l, 1);
        l += __shfl_xor(l, 2);
        l += __shfl_xor(l, 4);
        l += __shfl_xor(l, 8);
        float inv = 1.0f / l;
        int row = qrow_base + mt * 16 + quad * 4 + r;
        size_t ob = (rowbase + row) * 1024 + h * 64;
#pragma unroll
        for (int ntv = 0; ntv < 4; ++ntv)
          out[ob + ntv * 16 + l15] = (__bf16)(acc[mt][ntv][r] * inv);
      }
  }
}

extern "C" void kernel_launch(void* const* d_in, const int* in_sizes, int n_in,
                              void* d_out, int out_size, void* d_ws,
                              size_t ws_size, hipStream_t stream) {
  const float* x = (const float*)d_in[0];
  const float* qkv_w = (const float*)d_in[1];
  const float* qkv_b = (const float*)d_in[2];
  const float* out_w = (const float*)d_in[3];
  const float* out_b = (const float*)d_in[4];
  float* out = (float*)d_out;

  __bf16* qkv_ws = (__bf16*)d_ws;                  // 8192*3072
  __bf16* attn_ws = qkv_ws + (size_t)8192 * 3072;  // 8192*1024
  __bf16* xb = attn_ws + (size_t)8192 * 1024;      // 8192*1024
  __bf16* wqb = xb + (size_t)8192 * 1024;          // 3072*1024
  __bf16* wob = wqb + (size_t)3072 * 1024;         // 1024*1024

  convert3<<<6144, 256, 0, stream>>>(x, qkv_w, out_w, xb, wqb, wob);
  // QKV: M=8192, N=3072 -> 256^2 tiles, grid 12x32 = 384 blocks
  gemm256p<true><<<dim3(12, 32), 512, 0, stream>>>(xb, wqb, qkv_b, qkv_ws,
                                                   3072, 1024, 1024);
  attn_kernel<<<dim3(64, 8), 256, 0, stream>>>(qkv_ws, attn_ws);
  // out-proj: proven 128^2 kernel, grid 8x64 = 512 blocks
  gemm_bt<false><<<dim3(8, 64), 256, 0, stream>>>(attn_ws, wob, out_b, out,
                                                  8192, 1024, 1024, 0);
}

// Round 4
// 244.586 us; speedup vs baseline: 1.0282x; 1.0132x over previous
//
#include <hip/hip_runtime.h>

typedef __bf16 bf16x8 __attribute__((ext_vector_type(8)));
typedef __bf16 bf16x4 __attribute__((ext_vector_type(4)));
typedef float f32x4 __attribute__((ext_vector_type(4)));

typedef const __attribute__((address_space(1))) void* gptr_t;
typedef __attribute__((address_space(3))) void* lptr_t;

__device__ __forceinline__ f32x4 mfma16(bf16x8 a, bf16x8 b, f32x4 c) {
  return __builtin_amdgcn_mfma_f32_16x16x32_bf16(a, b, c, 0, 0, 0);
}

__device__ __forceinline__ void load_lds16(const __bf16* g, __bf16* l) {
  __builtin_amdgcn_global_load_lds((gptr_t)g, (lptr_t)l, 16, 0, 0);
}

__device__ __forceinline__ float fast_exp2(float x) {
#if __has_builtin(__builtin_amdgcn_exp2f)
  return __builtin_amdgcn_exp2f(x);  // raw v_exp_f32
#else
  return exp2f(x);
#endif
}

// round-to-nearest(+away) f32->bf16 for two values, packed into one dword
__device__ __forceinline__ unsigned pack_bf16(float f0, float f1) {
  unsigned u0 = __builtin_bit_cast(unsigned, f0) + 0x8000u;
  unsigned u1 = __builtin_bit_cast(unsigned, f1) + 0x8000u;
  return __builtin_amdgcn_perm(u1, u0, 0x07060302);
}

// ---- fp32 -> bf16 pre-convert: x (4096 blks), qkv_w (1536), out_w (512) ----
__global__ __launch_bounds__(256) void convert3(
    const float* __restrict__ x, const float* __restrict__ w1,
    const float* __restrict__ w2, __bf16* __restrict__ xb,
    __bf16* __restrict__ w1b, __bf16* __restrict__ w2b) {
  int bid = blockIdx.x;
  const float* src;
  __bf16* dst;
  int base;
  if (bid < 4096) {
    src = x; dst = xb; base = bid;
  } else if (bid < 5632) {
    src = w1; dst = w1b; base = bid - 4096;
  } else {
    src = w2; dst = w2b; base = bid - 5632;
  }
  size_t off = (size_t)base * 2048 + threadIdx.x * 8;
  float4 v0 = *(const float4*)(src + off);
  float4 v1 = *(const float4*)(src + off + 4);
  bf16x8 o = {(__bf16)v0.x, (__bf16)v0.y, (__bf16)v0.z, (__bf16)v0.w,
              (__bf16)v1.x, (__bf16)v1.y, (__bf16)v1.z, (__bf16)v1.w};
  *(bf16x8*)(dst + off) = o;
}

// C[M][N] = A[M][K] @ B[N][K]^T + bias[N]; A,B bf16; C bf16 or fp32.
// Proven m97-structure 128^2 kernel (713 TF on this shape — best of the
// 4 schedules tried in r0-r3; 8-phase ports were null, matching the guide's
// m232 open quadrant). r4 adds T1 XCD swizzle only (no sync-structure edit):
// orig blockIdx round-robins XCDs (block i -> XCD i%8); remapping
// id = (orig&7)*(nwg/8) + orig>>3 gives each XCD a CONTIGUOUS logical tile
// range (QKV: 192 tiles = 8 full A-row-groups -> 2 MB A-panel L2-resident
// per XCD). Bijective since nwg%8==0 at both call sites (1536, 512).
template <bool C_BF16>
__global__ __launch_bounds__(256) void gemm_bt(
    const __bf16* __restrict__ A, const __bf16* __restrict__ B,
    const float* __restrict__ bias, void* __restrict__ Cv, int M, int N,
    int K, int qcols) {
  __shared__ __bf16 As[2][128 * 32];
  __shared__ __bf16 Bs[2][128 * 32];

  const int tid = threadIdx.x;
  const int wid = tid >> 6;
  const int lane = tid & 63;
  const int l15 = lane & 15;
  const int quad = lane >> 4;

  // T1: XCD-aware bijective block swizzle (requires nwg % 8 == 0).
  const int nwg = gridDim.x * gridDim.y;
  int id = blockIdx.y * gridDim.x + blockIdx.x;
  id = (id & 7) * (nwg >> 3) + (id >> 3);
  const int bn = (id % gridDim.x) * 128;
  const int bm = (id / gridDim.x) * 128;

  const int wm = (wid & 1) * 64;
  const int wn = (wid >> 1) * 64;

  // staging: lane l -> row wid*16+(l>>2), global chunk (l&3)^((l>>3)&3)
  const int srow = wid * 16 + (lane >> 2);
  const int schunk = ((lane & 3) ^ ((lane >> 3) & 3)) * 8;
  const __bf16* gA = A + (size_t)(bm + srow) * K + schunk;
  const __bf16* gB = B + (size_t)(bn + srow) * K + schunk;
  const int ldsoff = wid * 16 * 32;  // wave-uniform

  // fragment-read chunk slot (loop-invariant; wm/i*16 vanish mod 4 after >>1)
  const int fsl = (quad ^ ((l15 >> 1) & 3)) * 8;

  f32x4 acc[4][4] = {};

  load_lds16(gA, &As[0][ldsoff]);
  load_lds16(gA + (size_t)64 * K, &As[0][64 * 32 + ldsoff]);
  load_lds16(gB, &Bs[0][ldsoff]);
  load_lds16(gB + (size_t)64 * K, &Bs[0][64 * 32 + ldsoff]);

  const int niter = K >> 5;
  for (int it = 0; it < niter; ++it) {
    const int cur = it & 1;
    __syncthreads();
    if (it + 1 < niter) {
      int k0 = (it + 1) << 5;
      load_lds16(gA + k0, &As[1 - cur][ldsoff]);
      load_lds16(gA + k0 + (size_t)64 * K, &As[1 - cur][64 * 32 + ldsoff]);
      load_lds16(gB + k0, &Bs[1 - cur][ldsoff]);
      load_lds16(gB + k0 + (size_t)64 * K, &Bs[1 - cur][64 * 32 + ldsoff]);
    }
    bf16x8 af[4], bf[4];
#pragma unroll
    for (int i = 0; i < 4; ++i)
      af[i] = *(const bf16x8*)(&As[cur][(wm + i * 16 + l15) * 32 + fsl]);
#pragma unroll
    for (int i = 0; i < 4; ++i)
      bf[i] = *(const bf16x8*)(&Bs[cur][(wn + i * 16 + l15) * 32 + fsl]);
#pragma unroll
    for (int mt = 0; mt < 4; ++mt)
#pragma unroll
      for (int nt = 0; nt < 4; ++nt)
        acc[mt][nt] = mfma16(af[mt], bf[nt], acc[mt][nt]);
  }

  const float sc = (bn < qcols) ? 0.18033688011112043f : 1.0f;
#pragma unroll
  for (int mt = 0; mt < 4; ++mt) {
#pragma unroll
    for (int nt = 0; nt < 4; ++nt) {
      int gc = bn + wn + nt * 16 + l15;
      float bv = bias[gc];
#pragma unroll
      for (int r = 0; r < 4; ++r) {
        int gr = bm + wm + mt * 16 + quad * 4 + r;
        float val = (acc[mt][nt][r] + bv) * sc;
        if constexpr (C_BF16)
          ((__bf16*)Cv)[(size_t)gr * N + gc] = (__bf16)val;
        else
          ((float*)Cv)[(size_t)gr * N + gc] = val;
      }
    }
  }
}

// exp + (optional causal mask) + deferred-l + packed P store in pi-layout.
template <bool MASK>
__device__ __forceinline__ void softmax_block(f32x4 (&s)[2][4],
                                              float (&lsum)[2][4],
                                              __bf16* __restrict__ psw,
                                              int kv0, int qrow_base, int quad,
                                              int l15) {
#pragma unroll
  for (int mt = 0; mt < 2; ++mt) {
#pragma unroll
    for (int r = 0; r < 4; ++r) {
      int prow = mt * 16 + quad * 4 + r;
      float p[4];
#pragma unroll
      for (int nt = 0; nt < 4; ++nt) {
        p[nt] = fast_exp2(s[mt][nt][r]);  // scale pre-folded into Q
        if constexpr (MASK) {
          if ((kv0 + nt * 16 + l15) > (qrow_base + prow)) p[nt] = 0.f;
        }
      }
      lsum[mt][r] += (p[0] + p[1]) + (p[2] + p[3]);
      uint2 w = {pack_bf16(p[0], p[1]), pack_bf16(p[2], p[3])};
      int o = ((l15 >> 1) ^ (prow & 7)) & 7;
      *(uint2*)(psw + prow * 64 + o * 8 + 4 * (l15 & 1)) = w;
    }
  }
}

// Flash attention, causal. qkv: (B*T, 3072) bf16 (Q pre-scaled by log2e/8);
// out: (B*T, 1024) bf16. Grid (64 bh, 8 pb) bh-fastest (KV L2-resident per
// XCD). Block 256 = 4 waves, BQ=128, BKV=64; phases {pb, 15-pb} -> 34 iters.
// P/V k-index permuted by pi(k)=4*(k&15)+(k>>4) -> packed P stores; XOR
// octet swizzles keep LDS bank-uniform. No-max softmax, deferred l.
// All LDS fragment offsets precomputed outside the kv-loop.
// r4: T5 s_setprio(1) around the QK^T and PV MFMA clusters. Waves here run
// barrier-free through QK->softmax->PV with 2-3 blocks/CU co-resident ->
// real phase diversity (m191-positive regime, not m190 lockstep-null).
__global__ __launch_bounds__(256) void attn_kernel(
    const __bf16* __restrict__ qkv, __bf16* __restrict__ out) {
  constexpr int T = 2048, C3 = 3072;
  constexpr int KVSTEP = 64 * C3;
  __shared__ __bf16 Ks[2][64 * 64];  // [kv][d]
  __shared__ __bf16 Vt[2][64 * 64];  // [d][pi(kv)]
  __shared__ __bf16 Ps[4][32 * 64];  // per-wave [qrow][pi(kv)]

  const int tid = threadIdx.x;
  const int wid = tid >> 6;
  const int lane = tid & 63;
  const int l15 = lane & 15;
  const int quad = lane >> 4;
  const int bh = blockIdx.x;  // 0..63 (fastest -> same XCD per bh)
  const int pb = blockIdx.y;  // 0..7
  const int b = bh >> 4, h = bh & 15;
  const size_t rowbase = (size_t)b * T;

  const int kr = tid >> 3;  // K staging: rows kr, kr+32
  const int kc = tid & 7;   // d-octet
  const int vj = tid >> 4;  // V staging: rows vj+16i -> pi-cols 4vj+i
  const int vn = tid & 15;  // d-nibble

  const __bf16* gk_base = qkv + rowbase * C3 + 1024 + h * 64 + kr * C3 + kc * 8;
  const __bf16* gv_base = qkv + rowbase * C3 + 2048 + h * 64 + vj * C3 + vn * 4;

  // ---- loop-invariant LDS offsets (elements) ----
  int ks_st0 = kr * 64 + ((kc ^ (kr & 7)) * 8);            // K store row kr
  int ks_st1 = (kr + 32) * 64 + ((kc ^ ((kr + 32) & 7)) * 8);
  int vt_st[4];
#pragma unroll
  for (int dd = 0; dd < 4; ++dd) {
    int d = 4 * vn + dd;
    vt_st[dd] = d * 64 + ((((vj >> 1) ^ (d & 7) ^ (d >> 3)) & 7) * 8) +
                4 * (vj & 1);
  }
  int kf_off[4][2];
#pragma unroll
  for (int nt = 0; nt < 4; ++nt)
#pragma unroll
    for (int ksi = 0; ksi < 2; ++ksi)
      kf_off[nt][ksi] =
          (nt * 16 + l15) * 64 + (((4 * ksi + quad) ^ (l15 & 7)) * 8);
  int pf_off[2][2];
#pragma unroll
  for (int mt = 0; mt < 2; ++mt)
#pragma unroll
    for (int ksi = 0; ksi < 2; ++ksi)
      pf_off[mt][ksi] =
          (mt * 16 + l15) * 64 + (((4 * ksi + quad) ^ (l15 & 7)) * 8);
  int vf_off[4][2];
#pragma unroll
  for (int ntv = 0; ntv < 4; ++ntv)
#pragma unroll
    for (int ksi = 0; ksi < 2; ++ksi) {
      int d = ntv * 16 + l15;
      vf_off[ntv][ksi] =
          d * 64 + ((((4 * ksi + quad) ^ (d & 7) ^ (d >> 3)) & 7) * 8);
    }

#pragma unroll 1
  for (int phase = 0; phase < 2; ++phase) {
    const int qp = phase == 0 ? pb : 15 - pb;
    const int q0 = qp * 128;
    const int ntiles = 2 * qp + 2;
    const int qrow_base = q0 + wid * 32;

    bf16x8 qf[2][2];
#pragma unroll
    for (int mt = 0; mt < 2; ++mt)
#pragma unroll
      for (int ksi = 0; ksi < 2; ++ksi)
        qf[mt][ksi] = *(const bf16x8*)(
            qkv + (rowbase + qrow_base + mt * 16 + l15) * C3 + h * 64 +
            ksi * 32 + quad * 8);

    f32x4 acc[2][4] = {};
    float lsum[2][4] = {};

    const __bf16* gk = gk_base;
    const __bf16* gv = gv_base;

    bf16x8 kreg[2];
    bf16x4 vreg[4];
    kreg[0] = *(const bf16x8*)(gk);
    kreg[1] = *(const bf16x8*)(gk + 32 * C3);
#pragma unroll
    for (int i = 0; i < 4; ++i)
      vreg[i] = *(const bf16x4*)(gv + i * 16 * C3);

    __syncthreads();  // previous phase's readers done

    for (int j = 0; j < ntiles; ++j) {
      __bf16* ksb = Ks[j & 1];
      __bf16* vtb = Vt[j & 1];
      *(bf16x8*)(ksb + ks_st0) = kreg[0];
      *(bf16x8*)(ksb + ks_st1) = kreg[1];
#pragma unroll
      for (int dd = 0; dd < 4; ++dd) {
        bf16x4 t = {vreg[0][dd], vreg[1][dd], vreg[2][dd], vreg[3][dd]};
        *(bf16x4*)(vtb + vt_st[dd]) = t;
      }
      if (j + 1 < ntiles) {
        gk += KVSTEP;
        gv += KVSTEP;
        kreg[0] = *(const bf16x8*)(gk);
        kreg[1] = *(const bf16x8*)(gk + 32 * C3);
#pragma unroll
        for (int i = 0; i < 4; ++i)
          vreg[i] = *(const bf16x4*)(gv + i * 16 * C3);
      }
      __syncthreads();

      const int kv0 = j * 64;
      // ---- S = Q K^T ----
      f32x4 s[2][4] = {};
      __builtin_amdgcn_s_setprio(1);
#pragma unroll
      for (int nt = 0; nt < 4; ++nt) {
#pragma unroll
        for (int ksi = 0; ksi < 2; ++ksi) {
          bf16x8 kf = *(const bf16x8*)(ksb + kf_off[nt][ksi]);
#pragma unroll
          for (int mt = 0; mt < 2; ++mt)
            s[mt][nt] = mfma16(qf[mt][ksi], kf, s[mt][nt]);
        }
      }
      __builtin_amdgcn_s_setprio(0);
      // ---- softmax (wave-uniform mask branch) ----
      if ((kv0 + 63) > qrow_base)
        softmax_block<true>(s, lsum, Ps[wid], kv0, qrow_base, quad, l15);
      else
        softmax_block<false>(s, lsum, Ps[wid], kv0, qrow_base, quad, l15);

      // ---- O += P V (per-wave Ps: no barrier) ----
      __builtin_amdgcn_s_setprio(1);
#pragma unroll
      for (int ksi = 0; ksi < 2; ++ksi) {
        bf16x8 pf[2];
#pragma unroll
        for (int mt = 0; mt < 2; ++mt)
          pf[mt] = *(const bf16x8*)(Ps[wid] + pf_off[mt][ksi]);
#pragma unroll
        for (int ntv = 0; ntv < 4; ++ntv) {
          bf16x8 vf = *(const bf16x8*)(vtb + vf_off[ntv][ksi]);
#pragma unroll
          for (int mt = 0; mt < 2; ++mt)
            acc[mt][ntv] = mfma16(pf[mt], vf, acc[mt][ntv]);
        }
      }
      __builtin_amdgcn_s_setprio(0);
    }

    // ---- phase epilogue: reduce l, normalize, store ----
#pragma unroll
    for (int mt = 0; mt < 2; ++mt)
#pragma unroll
      for (int r = 0; r < 4; ++r) {
        float l = lsum[mt][r];
        l += __shfl_xor(l, 1);
        l += __shfl_xor(l, 2);
        l += __shfl_xor(l, 4);
        l += __shfl_xor(l, 8);
        float inv = 1.0f / l;
        int row = qrow_base + mt * 16 + quad * 4 + r;
        size_t ob = (rowbase + row) * 1024 + h * 64;
#pragma unroll
        for (int ntv = 0; ntv < 4; ++ntv)
          out[ob + ntv * 16 + l15] = (__bf16)(acc[mt][ntv][r] * inv);
      }
  }
}

extern "C" void kernel_launch(void* const* d_in, const int* in_sizes, int n_in,
                              void* d_out, int out_size, void* d_ws,
                              size_t ws_size, hipStream_t stream) {
  const float* x = (const float*)d_in[0];
  const float* qkv_w = (const float*)d_in[1];
  const float* qkv_b = (const float*)d_in[2];
  const float* out_w = (const float*)d_in[3];
  const float* out_b = (const float*)d_in[4];
  float* out = (float*)d_out;

  __bf16* qkv_ws = (__bf16*)d_ws;                  // 8192*3072
  __bf16* attn_ws = qkv_ws + (size_t)8192 * 3072;  // 8192*1024
  __bf16* xb = attn_ws + (size_t)8192 * 1024;      // 8192*1024
  __bf16* wqb = xb + (size_t)8192 * 1024;          // 3072*1024
  __bf16* wob = wqb + (size_t)3072 * 1024;         // 1024*1024

  convert3<<<6144, 256, 0, stream>>>(x, qkv_w, out_w, xb, wqb, wob);
  // QKV: grid 24x64 = 1536 blocks (%8==0 -> bijective XCD swizzle)
  gemm_bt<true><<<dim3(24, 64), 256, 0, stream>>>(xb, wqb, qkv_b, qkv_ws,
                                                  8192, 3072, 1024, 1024);
  attn_kernel<<<dim3(64, 8), 256, 0, stream>>>(qkv_ws, attn_ws);
  // out-proj: grid 8x64 = 512 blocks (%8==0)
  gemm_bt<false><<<dim3(8, 64), 256, 0, stream>>>(attn_ws, wob, out_b, out,
                                                  8192, 1024, 1024, 0);
}